// Round 2
// baseline (62.861 us; speedup 1.0000x reference)
//
#include <hip/hip_runtime.h>
#include <math.h>

// SimpleMamba: s_t = A*s_{t-1} + B*x_t ; y_t = tanh(C*s_t), per-channel.
// L=8192 timesteps, D=2048 channels, f32.
// 3-phase chunked parallel scan: NC=256 chunks of CL=32 steps.
// Chunk coefficient A^32 stays finite for |A| < 16 (max|A| ~ 3.9) -> no 0*Inf NaN.

#define LL 8192
#define DD 2048
#define CL 32
#define NC (LL / CL)   // 256 chunks
#define G4 (DD / 4)    // 512 float4 channel-groups per row

// ---------------- Phase 1: per-chunk local end-state (from s=0) ----------------
__global__ __launch_bounds__(256) void mamba_p1(
    const float4* __restrict__ x4, const float4* __restrict__ A4,
    const float4* __restrict__ B4, float4* __restrict__ loc4)
{
    int lin   = blockIdx.x * 256 + threadIdx.x;   // NC * G4 threads
    int chunk = lin >> 9;                         // / G4 (=512)
    int grp   = lin & (G4 - 1);

    float4 a = A4[grp];
    float4 b = B4[grp];
    float sx = 0.f, sy = 0.f, sz = 0.f, sw = 0.f;

    const float4* xp = x4 + (size_t)chunk * CL * G4 + grp;
    #pragma unroll
    for (int t = 0; t < CL; ++t) {
        float4 v = xp[(size_t)t * G4];
        sx = fmaf(a.x, sx, b.x * v.x);
        sy = fmaf(a.y, sy, b.y * v.y);
        sz = fmaf(a.z, sz, b.z * v.z);
        sw = fmaf(a.w, sw, b.w * v.w);
    }
    loc4[(size_t)chunk * G4 + grp] = make_float4(sx, sy, sz, sw);
}

// ---------------- Phase 2: serial scan over chunks (per channel-group) ----------------
// carry[c] = state entering chunk c;  carry[c+1] = A^CL * carry[c] + loc[c]
__global__ __launch_bounds__(256) void mamba_p2(
    const float4* __restrict__ A4, const float4* __restrict__ loc4,
    float4* __restrict__ car4)
{
    int grp = blockIdx.x * 256 + threadIdx.x;     // 0..G4-1 over 2 blocks
    float4 a = A4[grp];

    // p = A^32 via repeated squaring (5 squarings)
    float px = a.x, py = a.y, pz = a.z, pw = a.w;
    #pragma unroll
    for (int i = 0; i < 5; ++i) { px *= px; py *= py; pz *= pz; pw *= pw; }

    float cx = 0.f, cy = 0.f, cz = 0.f, cw = 0.f;

    for (int c0 = 0; c0 < NC; c0 += 8) {
        float4 lv[8];
        #pragma unroll
        for (int k = 0; k < 8; ++k)
            lv[k] = loc4[(size_t)(c0 + k) * G4 + grp];   // batched: 8 loads in flight
        #pragma unroll
        for (int k = 0; k < 8; ++k) {
            car4[(size_t)(c0 + k) * G4 + grp] = make_float4(cx, cy, cz, cw);
            cx = fmaf(px, cx, lv[k].x);
            cy = fmaf(py, cy, lv[k].y);
            cz = fmaf(pz, cz, lv[k].z);
            cw = fmaf(pw, cw, lv[k].w);
        }
    }
}

// ---------------- Phase 3: recompute recurrence from carry, emit tanh(C*s) ----------------
__global__ __launch_bounds__(256) void mamba_p3(
    const float4* __restrict__ x4, const float4* __restrict__ A4,
    const float4* __restrict__ B4, const float4* __restrict__ C4,
    const float4* __restrict__ car4, float4* __restrict__ y4)
{
    int lin   = blockIdx.x * 256 + threadIdx.x;
    int chunk = lin >> 9;
    int grp   = lin & (G4 - 1);

    float4 a = A4[grp];
    float4 b = B4[grp];
    float4 c = C4[grp];
    float4 s0 = car4[(size_t)chunk * G4 + grp];
    float sx = s0.x, sy = s0.y, sz = s0.z, sw = s0.w;

    const float4* xp = x4 + (size_t)chunk * CL * G4 + grp;
    float4*       yp = y4 + (size_t)chunk * CL * G4 + grp;

    #pragma unroll 8
    for (int t = 0; t < CL; ++t) {
        float4 v = xp[(size_t)t * G4];
        sx = fmaf(a.x, sx, b.x * v.x);
        sy = fmaf(a.y, sy, b.y * v.y);
        sz = fmaf(a.z, sz, b.z * v.z);
        sw = fmaf(a.w, sw, b.w * v.w);
        float4 o = make_float4(tanhf(c.x * sx), tanhf(c.y * sy),
                               tanhf(c.z * sz), tanhf(c.w * sw));
        yp[(size_t)t * G4] = o;
    }
}

extern "C" void kernel_launch(void* const* d_in, const int* in_sizes, int n_in,
                              void* d_out, int out_size, void* d_ws, size_t ws_size,
                              hipStream_t stream)
{
    const float4* x4 = (const float4*)d_in[0];   // [L, D] f32
    const float4* A4 = (const float4*)d_in[1];   // [D]
    const float4* B4 = (const float4*)d_in[2];   // [D]
    const float4* C4 = (const float4*)d_in[3];   // [D]
    float4* y4 = (float4*)d_out;                 // [L, D] f32

    // workspace: loc (NC*D f32 = 2 MiB) + carry (2 MiB)
    float4* loc4 = (float4*)d_ws;
    float4* car4 = loc4 + (size_t)NC * G4;

    const int nthreads = NC * G4;                // 131072
    mamba_p1<<<nthreads / 256, 256, 0, stream>>>(x4, A4, B4, loc4);
    mamba_p2<<<G4 / 256, 256, 0, stream>>>(A4, loc4, car4);
    mamba_p3<<<nthreads / 256, 256, 0, stream>>>(x4, A4, B4, C4, car4, y4);
}

// Round 3
// 48.391 us; speedup vs baseline: 1.2990x; 1.2990x over previous
//
#include <hip/hip_runtime.h>
#include <math.h>

// SimpleMamba: s_t = A*s_{t-1} + B*x_t ; y_t = tanh(C*s_t), per-channel.
// L=8192 timesteps, D=2048 channels, f32.
// 3-phase chunked parallel scan: NC=256 chunks of CL=32 steps.
// CL=32 pinned by f32 overflow: chunk-local sums ~A^31*|Bx| stay finite (max|A|~3.9),
// CL=64 would overflow. Tree-scan p2 is NaN-unsafe (inf-inf in compose for |A|>1
// channels) -> p2 stays a flat serial chain, optimized for load latency only.

#define LL 8192
#define DD 2048
#define CL 32
#define NC (LL / CL)   // 256 chunks
#define G4 (DD / 4)    // 512 float4 channel-groups per row

// ---------------- Phase 1: per-chunk local end-state (from s=0) ----------------
__global__ __launch_bounds__(256) void mamba_p1(
    const float4* __restrict__ x4, const float4* __restrict__ A4,
    const float4* __restrict__ B4, float4* __restrict__ loc4)
{
    int lin   = blockIdx.x * 256 + threadIdx.x;   // NC * G4 threads
    int chunk = lin >> 9;                         // / G4 (=512)
    int grp   = lin & (G4 - 1);

    float4 a = A4[grp];
    float4 b = B4[grp];
    float sx = 0.f, sy = 0.f, sz = 0.f, sw = 0.f;

    const float4* xp = x4 + (size_t)chunk * CL * G4 + grp;
    #pragma unroll
    for (int t = 0; t < CL; ++t) {
        float4 v = xp[(size_t)t * G4];
        sx = fmaf(a.x, sx, b.x * v.x);
        sy = fmaf(a.y, sy, b.y * v.y);
        sz = fmaf(a.z, sz, b.z * v.z);
        sw = fmaf(a.w, sw, b.w * v.w);
    }
    loc4[(size_t)chunk * G4 + grp] = make_float4(sx, sy, sz, sw);
}

// ---------------- Phase 2: serial scan over chunks, one thread per CHANNEL ----------------
// carry[c] = state entering chunk c; carry[c+1] = A^CL * carry[c] + loc[c].
// 2048 threads over 32 blocks (32 CUs). 64-deep load batches -> 4 latency stalls
// instead of 32 (this phase is latency-bound: only 2 MiB of traffic).
__global__ __launch_bounds__(64) void mamba_p2(
    const float* __restrict__ A, const float* __restrict__ loc,
    float* __restrict__ car)
{
    int ch = blockIdx.x * 64 + threadIdx.x;       // 0..DD-1
    float a = A[ch];

    // p = A^32 via 5 squarings (finite: 3.9^32 ~ 8e18)
    float p = a;
    #pragma unroll
    for (int i = 0; i < 5; ++i) p *= p;

    float c = 0.f;
    for (int c0 = 0; c0 < NC; c0 += 64) {
        float lv[64];
        #pragma unroll
        for (int k = 0; k < 64; ++k)
            lv[k] = loc[(size_t)(c0 + k) * DD + ch];   // 64 loads in flight
        #pragma unroll
        for (int k = 0; k < 64; ++k) {
            car[(size_t)(c0 + k) * DD + ch] = c;
            c = fmaf(p, c, lv[k]);                     // lv[k] always finite -> no inf-inf
        }
    }
}

// ---------------- Phase 3: recompute recurrence from carry, emit tanh(C*s) ----------------
// fast tanh: tanh(z) = 1 - 2/(exp2(2z*log2e)+1); v_exp_f32 + v_rcp_f32.
// Exact saturation at +-inf; ~1e-7 rel error (threshold is 2e-2).
__device__ __forceinline__ float fast_tanh(float z)
{
    float e = __builtin_amdgcn_exp2f(z * 2.885390081777927f);  // 2*log2(e)
    return 1.0f - 2.0f * __builtin_amdgcn_rcpf(e + 1.0f);
}

__global__ __launch_bounds__(256) void mamba_p3(
    const float4* __restrict__ x4, const float4* __restrict__ A4,
    const float4* __restrict__ B4, const float4* __restrict__ C4,
    const float4* __restrict__ car4, float4* __restrict__ y4)
{
    int lin   = blockIdx.x * 256 + threadIdx.x;
    int chunk = lin >> 9;
    int grp   = lin & (G4 - 1);

    float4 a = A4[grp];
    float4 b = B4[grp];
    float4 c = C4[grp];
    float4 s0 = car4[(size_t)chunk * G4 + grp];
    float sx = s0.x, sy = s0.y, sz = s0.z, sw = s0.w;

    const float4* xp = x4 + (size_t)chunk * CL * G4 + grp;
    float4*       yp = y4 + (size_t)chunk * CL * G4 + grp;

    #pragma unroll 8
    for (int t = 0; t < CL; ++t) {
        float4 v = xp[(size_t)t * G4];
        sx = fmaf(a.x, sx, b.x * v.x);
        sy = fmaf(a.y, sy, b.y * v.y);
        sz = fmaf(a.z, sz, b.z * v.z);
        sw = fmaf(a.w, sw, b.w * v.w);
        float4 o = make_float4(fast_tanh(c.x * sx), fast_tanh(c.y * sy),
                               fast_tanh(c.z * sz), fast_tanh(c.w * sw));
        yp[(size_t)t * G4] = o;
    }
}

extern "C" void kernel_launch(void* const* d_in, const int* in_sizes, int n_in,
                              void* d_out, int out_size, void* d_ws, size_t ws_size,
                              hipStream_t stream)
{
    const float*  Af = (const float*)d_in[1];
    const float4* x4 = (const float4*)d_in[0];   // [L, D] f32
    const float4* A4 = (const float4*)d_in[1];   // [D]
    const float4* B4 = (const float4*)d_in[2];   // [D]
    const float4* C4 = (const float4*)d_in[3];   // [D]
    float4* y4 = (float4*)d_out;                 // [L, D] f32

    // workspace: loc (NC*D f32 = 2 MiB) + carry (2 MiB)
    float*  locf = (float*)d_ws;
    float4* loc4 = (float4*)d_ws;
    float*  carf = locf + (size_t)NC * DD;
    float4* car4 = (float4*)carf;

    const int nthreads = NC * G4;                // 131072
    mamba_p1<<<nthreads / 256, 256, 0, stream>>>(x4, A4, B4, loc4);
    mamba_p2<<<DD / 64, 64, 0, stream>>>(Af, locf, carf);
    mamba_p3<<<nthreads / 256, 256, 0, stream>>>(x4, A4, B4, C4, car4, y4);
}